// Round 5
// baseline (143.166 us; speedup 1.0000x reference)
//
#include <hip/hip_runtime.h>
#include <hip/hip_bf16.h>
#include <stdint.h>

#define NPTS 2048
#define DM 256
#define NH 4
#define DH 64
#define KK 1024

// ws layout (ushort units):
//  Qh bf16 [4][2048][64] @ 0
//  Ql bf16               @ 1*524288
//  Kh bf16               @ 2*524288
//  Kl bf16               @ 3*524288
//  Vt bf16 [4][64][2048] @ 4*524288   (transposed: channel-major)
#define QH_OFF 0
#define QL_OFF (NH*NPTS*DH)
#define KH_OFF (2*NH*NPTS*DH)
#define KL_OFF (3*NH*NPTS*DH)
#define VT_OFF (4*NH*NPTS*DH)

typedef __attribute__((ext_vector_type(8)))  short bf16x8;
typedef __attribute__((ext_vector_type(4)))  float f32x4;

__device__ inline ushort bf16rn(float f) {
    uint32_t u = __float_as_uint(f);
    uint32_t r = (u + 0x7FFFu + ((u >> 16) & 1u)) >> 16;
    return (ushort)r;
}
__device__ inline float bf16tof(ushort h) {
    return __uint_as_float(((uint32_t)h) << 16);
}
__device__ inline uint32_t f2u(float f) {
    uint32_t x = __float_as_uint(f);
    return (x & 0x80000000u) ? ~x : (x | 0x80000000u);
}
__device__ inline float u2f(uint32_t u) {
    uint32_t x = (u & 0x80000000u) ? (u ^ 0x80000000u) : ~u;
    return __uint_as_float(x);
}

// ---------------- Kernel 1: projections + rotary + bf16 hi/lo split + V^T ----------------
// grid (256, 3), block 256. z: 0=Q(rotary+scale->Qh/Ql), 1=K(rotary->Kh/Kl), 2=V(bf16 transposed)
__global__ __launch_bounds__(256) void proj_rope_kernel(
    const float* __restrict__ xq, const float* __restrict__ xk, const float* __restrict__ xv,
    const float* __restrict__ emb,
    const float* __restrict__ Wq, const float* __restrict__ bq,
    const float* __restrict__ Wk, const float* __restrict__ bk,
    const float* __restrict__ Wv, const float* __restrict__ bv,
    ushort* __restrict__ wsu)
{
    const int z = blockIdx.y;
    const int n0 = blockIdx.x * 8;
    const float* X = (z==0) ? xq : (z==1) ? xk : xv;
    const float* W = (z==0) ? Wq : (z==1) ? Wk : Wv;
    const float* B = (z==0) ? bq : (z==1) ? bk : bv;

    __shared__ float s_in[8][DM];
    {
        const float4* X4 = (const float4*)(X + (size_t)n0 * DM);
        float4* s4 = (float4*)&s_in[0][0];
        #pragma unroll
        for (int i = 0; i < 2; i++) {
            int f = threadIdx.x + 256*i;
            s4[f] = X4[f];
        }
    }
    __syncthreads();

    const int c = threadIdx.x;
    const int h = c >> 6, d = c & 63;
    const float bias = B[c];
    float acc[8];
    #pragma unroll
    for (int r = 0; r < 8; r++) acc[r] = bias;

    const float4* W4 = (const float4*)(W + (size_t)c * DM);
    #pragma unroll 4
    for (int k4 = 0; k4 < DM/4; k4++) {
        float4 w = W4[k4];
        #pragma unroll
        for (int r = 0; r < 8; r++) {
            float4 sv = *(const float4*)&s_in[r][k4*4];
            acc[r] = fmaf(sv.x, w.x, acc[r]);
            acc[r] = fmaf(sv.y, w.y, acc[r]);
            acc[r] = fmaf(sv.z, w.z, acc[r]);
            acc[r] = fmaf(sv.w, w.w, acc[r]);
        }
    }

    if (z < 2) {
        const int p = d >> 1;
        #pragma unroll
        for (int r = 0; r < 8; r++) {
            float th = emb[(size_t)(n0 + r)*(DM/2) + h*32 + p];
            float cs = cosf(th), sn = sinf(th);
            float partner = __shfl_xor(acc[r], 1);
            acc[r] = (d & 1) ? (acc[r]*cs + partner*sn) : (acc[r]*cs - partner*sn);
            if (z == 0) acc[r] *= 0.125f;   // 1/sqrt(64) folded into Q
        }
        // bf16 hi/lo split -> ws
        ushort* hi = wsu + ((z==0) ? QH_OFF : KH_OFF);
        ushort* lo = wsu + ((z==0) ? QL_OFF : KL_OFF);
        #pragma unroll
        for (int r = 0; r < 8; r++) {
            size_t idx = ((size_t)(h*NPTS + n0 + r))*DH + d;
            ushort hb = bf16rn(acc[r]);
            float res = acc[r] - bf16tof(hb);
            hi[idx] = hb;
            lo[idx] = bf16rn(res);
        }
    } else {
        // V: transpose via LDS, write bf16 Vt[channel c][n0..n0+7]
        __syncthreads();
        #pragma unroll
        for (int r = 0; r < 8; r++) s_in[r][c] = acc[r];
        __syncthreads();
        ushort tmp[8];
        #pragma unroll
        for (int r = 0; r < 8; r++) tmp[r] = bf16rn(s_in[r][c]);
        *(bf16x8*)(wsu + VT_OFF + (size_t)c*NPTS + n0) = *(bf16x8*)tmp;
    }
}

// ---------------- Kernel 2: fused scores (MFMA) + top-k + softmax + probs + PV ----------------
// grid (256, 4), block 512 (8 waves). Block = 8 query rows of one head.
// LDS: S[8][2048] f32 = 64KB. Per-row overlay after topk: bytes [0,4096) = P bf16,
// bytes [4096,6272) = PV partials [8][68] f32.
__global__ __launch_bounds__(512, 4) void fused_attn_kernel(const ushort* __restrict__ wsu,
                                                            float* __restrict__ out)
{
    const int h  = blockIdx.y;
    const int n0 = blockIdx.x * 8;
    float* sp = out + (size_t)NPTS*DM;
    __shared__ float S[8][NPTS];   // exactly 65536 B

    const int w  = threadIdx.x >> 6, l = threadIdx.x & 63;
    const int cl = l & 15, cg = l >> 4;

    // ========== phase A: scores rows 0..7 x cols [256w, 256w+256) ==========
    // Swapped operands: A = K (16 cols/tile, full), B = Q (rows dup: col -> qrow = cl&7).
    // C[lane,reg]: K-col = col0+16t+4*cg+reg, q-row = cl (cl<8 valid).
    {
        const size_t qbase = ((size_t)(h*NPTS + n0 + (cl & 7)))*DH + 8*cg;
        bf16x8 qbh[2], qbl[2];
        #pragma unroll
        for (int s = 0; s < 2; s++) {
            qbh[s] = *(const bf16x8*)(wsu + QH_OFF + qbase + 32*s);
            qbl[s] = *(const bf16x8*)(wsu + QL_OFF + qbase + 32*s);
        }
        const int col0 = 256*w;
        #pragma unroll 4
        for (int t = 0; t < 16; t++) {
            const size_t kbase = ((size_t)(h*NPTS + col0 + 16*t + cl))*DH + 8*cg;
            f32x4 acc = {0.f, 0.f, 0.f, 0.f};
            #pragma unroll
            for (int s = 0; s < 2; s++) {
                bf16x8 ah = *(const bf16x8*)(wsu + KH_OFF + kbase + 32*s);
                bf16x8 al = *(const bf16x8*)(wsu + KL_OFF + kbase + 32*s);
                acc = __builtin_amdgcn_mfma_f32_16x16x32_bf16(ah, qbh[s], acc, 0, 0, 0);
                acc = __builtin_amdgcn_mfma_f32_16x16x32_bf16(ah, qbl[s], acc, 0, 0, 0);
                acc = __builtin_amdgcn_mfma_f32_16x16x32_bf16(al, qbh[s], acc, 0, 0, 0);
            }
            if (cl < 8) {
                // logical 16B chunk (64w+4t+cg), XOR-swizzled by q-row to spread banks
                uint32_t byte = (1024u*(uint32_t)w + 64u*(uint32_t)t + 16u*(uint32_t)cg)
                                ^ ((uint32_t)cl << 4);
                *(f32x4*)((char*)&S[cl][0] + byte) = acc;
            }
        }
    }

    // prefetch Vt A-frags for PV kstep 0 (no LDS dependency -> overlaps the barrier+search)
    const ushort* Vt = wsu + VT_OFF + (size_t)h*DH*NPTS;
    const int m0 = w * 256;
    bf16x8 vpre[4];
    #pragma unroll
    for (int dt = 0; dt < 4; dt++)
        vpre[dt] = *(const bf16x8*)(Vt + ((size_t)(16*dt + cl))*NPTS + (m0 + 8*cg));

    __syncthreads();   // scores visible

    // ========== phase B: per-wave exact top-1024 + softmax on row w ==========
    const uint32_t sw = ((uint32_t)w) << 4;
    uint32_t u[32];
    #pragma unroll
    for (int j = 0; j < 8; j++) {
        f32x4 v = *(const f32x4*)((const char*)&S[w][0] + ((16u*(uint32_t)(l + 64*j)) ^ sw));
        u[4*j+0] = f2u(v[0]); u[4*j+1] = f2u(v[1]); u[4*j+2] = f2u(v[2]); u[4*j+3] = f2u(v[3]);
    }

    // row max
    uint32_t mu = 0u;
    #pragma unroll
    for (int j = 0; j < 32; j++) mu = (u[j] > mu) ? u[j] : mu;
    #pragma unroll
    for (int off = 32; off; off >>= 1) {
        uint32_t o = (uint32_t)__shfl_xor((int)mu, off);
        mu = (o > mu) ? o : mu;
    }
    const float mx = u2f(mu);

    // 2-bit radix search for exact 1024-th largest key (16 dependent steps, early exit)
    uint32_t cur = 0u;
    for (int bit = 30; bit >= 0; bit -= 2) {
        const uint32_t cA = cur | (3u << bit);
        const uint32_t cB = cur | (2u << bit);
        const uint32_t cC = cur | (1u << bit);
        int nA = 0, nB = 0, nC = 0;
        #pragma unroll
        for (int j = 0; j < 32; j++) {
            nA += (int)__popcll(__ballot(u[j] >= cA));
            nB += (int)__popcll(__ballot(u[j] >= cB));
            nC += (int)__popcll(__ballot(u[j] >= cC));
        }
        if (nA >= KK)      { cur = cA; if (nA == KK) break; }
        else if (nB >= KK) { cur = cB; if (nB == KK) break; }
        else if (nC >= KK) { cur = cC; if (nC == KK) break; }
    }

    // softmax over selected; exp overwrites u[]
    float zsum = 0.f;
    #pragma unroll
    for (int j = 0; j < 32; j++) {
        bool sel = (u[j] >= cur);
        float ev = sel ? __expf(u2f(u[j]) - mx) : 0.f;
        u[j] = __float_as_uint(ev);
        zsum += ev;
    }
    #pragma unroll
    for (int off = 32; off; off >>= 1) zsum += __shfl_xor(zsum, off);
    const float rz = 1.f / zsum;

    // probs -> global (dense row) + bf16 P overlaid into own S row's first 4KB (swizzled)
    float* grow = sp + ((size_t)(h*NPTS + n0 + w))*NPTS;
    #pragma unroll
    for (int j = 0; j < 8; j++) {
        float4 p;
        p.x = __uint_as_float(u[4*j+0]) * rz;
        p.y = __uint_as_float(u[4*j+1]) * rz;
        p.z = __uint_as_float(u[4*j+2]) * rz;
        p.w = __uint_as_float(u[4*j+3]) * rz;
        ((float4*)grow)[l + 64*j] = p;
        uint32_t pk0 = ((uint32_t)bf16rn(p.y) << 16) | (uint32_t)bf16rn(p.x);
        uint32_t pk1 = ((uint32_t)bf16rn(p.w) << 16) | (uint32_t)bf16rn(p.z);
        *(uint2*)((char*)&S[w][0] + ((8u*(uint32_t)(l + 64*j)) ^ sw)) = make_uint2(pk0, pk1);
    }
    __syncthreads();   // all P rows ready

    // ========== phase C: PV via MFMA. wave w covers m in [256w, 256w+256) ==========
    const int prow = cl & 7;
    const char* pbase = (const char*)&S[prow][0];
    const uint32_t psw = ((uint32_t)prow) << 4;
    f32x4 pacc[4];
    #pragma unroll
    for (int dt = 0; dt < 4; dt++) pacc[dt] = (f32x4){0.f, 0.f, 0.f, 0.f};

    {   // s = 0 uses prefetched A-frags
        bf16x8 bfrag = *(const bf16x8*)(pbase + ((2u*(uint32_t)(m0 + 8*cg)) ^ psw));
        #pragma unroll
        for (int dt = 0; dt < 4; dt++)
            pacc[dt] = __builtin_amdgcn_mfma_f32_16x16x32_bf16(vpre[dt], bfrag, pacc[dt], 0, 0, 0);
    }
    for (int s = 1; s < 8; s++) {
        const int mk = m0 + 32*s + 8*cg;
        bf16x8 bfrag = *(const bf16x8*)(pbase + ((2u*(uint32_t)mk) ^ psw));
        #pragma unroll
        for (int dt = 0; dt < 4; dt++) {
            bf16x8 afrag = *(const bf16x8*)(Vt + ((size_t)(16*dt + cl))*NPTS + mk);
            pacc[dt] = __builtin_amdgcn_mfma_f32_16x16x32_bf16(afrag, bfrag, pacc[dt], 0, 0, 0);
        }
    }

    // partials into own row's bytes [4096, 4096+8*68*4): [qrow=cl][d], stride 68 breaks conflicts
    if (cl < 8) {
        float* part = (float*)((char*)S + (size_t)w*(NPTS*4) + 4096);
        #pragma unroll
        for (int dt = 0; dt < 4; dt++)
            #pragma unroll
            for (int r4 = 0; r4 < 4; r4++)
                part[cl*68 + 16*dt + 4*cg + r4] = pacc[dt][r4];
    }
    __syncthreads();

    {   // final reduce: thread (r=w, d=l) sums 8 wave-partials
        const int r = w, d = l;
        float ssum = 0.f;
        #pragma unroll
        for (int wv = 0; wv < 8; wv++)
            ssum += *(const float*)((const char*)S + (size_t)wv*(NPTS*4) + 4096 + 4u*(uint32_t)(r*68 + d));
        out[(size_t)(n0 + r)*DM + h*DH + d] = ssum;
    }
}

extern "C" void kernel_launch(void* const* d_in, const int* in_sizes, int n_in,
                              void* d_out, int out_size, void* d_ws, size_t ws_size,
                              hipStream_t stream)
{
    const float* xq  = (const float*)d_in[0];
    const float* xk  = (const float*)d_in[1];
    const float* xv  = (const float*)d_in[2];
    const float* emb = (const float*)d_in[3];
    const float* Wq  = (const float*)d_in[4];
    const float* bq  = (const float*)d_in[5];
    const float* Wk  = (const float*)d_in[6];
    const float* bk  = (const float*)d_in[7];
    const float* Wv  = (const float*)d_in[8];
    const float* bv  = (const float*)d_in[9];
    float* out  = (float*)d_out;
    ushort* wsu = (ushort*)d_ws;   // needs 5 MiB

    proj_rope_kernel<<<dim3(NPTS/8, 3), 256, 0, stream>>>(xq, xk, xv, emb, Wq, bq, Wk, bk, Wv, bv, wsu);
    fused_attn_kernel<<<dim3(NPTS/8, NH), 512, 0, stream>>>(wsu, out);
}

// Round 6
// 114.546 us; speedup vs baseline: 1.2499x; 1.2499x over previous
//
#include <hip/hip_runtime.h>
#include <hip/hip_bf16.h>
#include <stdint.h>

#define NPTS 2048
#define DM 256
#define NH 4
#define DH 64
#define KK 1024

// ws layout (ushort units):
//  Qh bf16 [4][2048][64] @ 0
//  Ql bf16               @ 1*524288
//  Kh bf16               @ 2*524288
//  Kl bf16               @ 3*524288
//  Vt bf16 [4][64][2048] @ 4*524288   (transposed: channel-major)
#define QH_OFF 0
#define QL_OFF (NH*NPTS*DH)
#define KH_OFF (2*NH*NPTS*DH)
#define KL_OFF (3*NH*NPTS*DH)
#define VT_OFF (4*NH*NPTS*DH)

typedef __attribute__((ext_vector_type(8)))  short bf16x8;
typedef __attribute__((ext_vector_type(4)))  float f32x4;

__device__ inline ushort bf16rn(float f) {
    uint32_t u = __float_as_uint(f);
    uint32_t r = (u + 0x7FFFu + ((u >> 16) & 1u)) >> 16;
    return (ushort)r;
}
__device__ inline float bf16tof(ushort h) {
    return __uint_as_float(((uint32_t)h) << 16);
}
__device__ inline uint32_t f2u(float f) {
    uint32_t x = __float_as_uint(f);
    return (x & 0x80000000u) ? ~x : (x | 0x80000000u);
}
__device__ inline float u2f(uint32_t u) {
    uint32_t x = (u & 0x80000000u) ? (u ^ 0x80000000u) : ~u;
    return __uint_as_float(x);
}

// ---------------- Kernel 1: projections + rotary + bf16 hi/lo split + V^T ----------------
// grid (256, 3), block 256. z: 0=Q(rotary+scale->Qh/Ql), 1=K(rotary->Kh/Kl), 2=V(bf16 transposed)
__global__ __launch_bounds__(256) void proj_rope_kernel(
    const float* __restrict__ xq, const float* __restrict__ xk, const float* __restrict__ xv,
    const float* __restrict__ emb,
    const float* __restrict__ Wq, const float* __restrict__ bq,
    const float* __restrict__ Wk, const float* __restrict__ bk,
    const float* __restrict__ Wv, const float* __restrict__ bv,
    ushort* __restrict__ wsu)
{
    const int z = blockIdx.y;
    const int n0 = blockIdx.x * 8;
    const float* X = (z==0) ? xq : (z==1) ? xk : xv;
    const float* W = (z==0) ? Wq : (z==1) ? Wk : Wv;
    const float* B = (z==0) ? bq : (z==1) ? bk : bv;

    __shared__ float s_in[8][DM];
    {
        const float4* X4 = (const float4*)(X + (size_t)n0 * DM);
        float4* s4 = (float4*)&s_in[0][0];
        #pragma unroll
        for (int i = 0; i < 2; i++) {
            int f = threadIdx.x + 256*i;
            s4[f] = X4[f];
        }
    }
    __syncthreads();

    const int c = threadIdx.x;
    const int h = c >> 6, d = c & 63;
    const float bias = B[c];
    float acc[8];
    #pragma unroll
    for (int r = 0; r < 8; r++) acc[r] = bias;

    const float4* W4 = (const float4*)(W + (size_t)c * DM);
    #pragma unroll 4
    for (int k4 = 0; k4 < DM/4; k4++) {
        float4 w = W4[k4];
        #pragma unroll
        for (int r = 0; r < 8; r++) {
            float4 sv = *(const float4*)&s_in[r][k4*4];
            acc[r] = fmaf(sv.x, w.x, acc[r]);
            acc[r] = fmaf(sv.y, w.y, acc[r]);
            acc[r] = fmaf(sv.z, w.z, acc[r]);
            acc[r] = fmaf(sv.w, w.w, acc[r]);
        }
    }

    if (z < 2) {
        const int p = d >> 1;
        #pragma unroll
        for (int r = 0; r < 8; r++) {
            float th = emb[(size_t)(n0 + r)*(DM/2) + h*32 + p];
            float cs = cosf(th), sn = sinf(th);
            float partner = __shfl_xor(acc[r], 1);
            acc[r] = (d & 1) ? (acc[r]*cs + partner*sn) : (acc[r]*cs - partner*sn);
            if (z == 0) acc[r] *= 0.125f;   // 1/sqrt(64) folded into Q
        }
        // bf16 hi/lo split -> ws
        ushort* hi = wsu + ((z==0) ? QH_OFF : KH_OFF);
        ushort* lo = wsu + ((z==0) ? QL_OFF : KL_OFF);
        #pragma unroll
        for (int r = 0; r < 8; r++) {
            size_t idx = ((size_t)(h*NPTS + n0 + r))*DH + d;
            ushort hb = bf16rn(acc[r]);
            float res = acc[r] - bf16tof(hb);
            hi[idx] = hb;
            lo[idx] = bf16rn(res);
        }
    } else {
        // V: transpose via LDS, write bf16 Vt[channel c][n0..n0+7]
        __syncthreads();
        #pragma unroll
        for (int r = 0; r < 8; r++) s_in[r][c] = acc[r];
        __syncthreads();
        ushort tmp[8];
        #pragma unroll
        for (int r = 0; r < 8; r++) tmp[r] = bf16rn(s_in[r][c]);
        *(bf16x8*)(wsu + VT_OFF + (size_t)c*NPTS + n0) = *(bf16x8*)tmp;
    }
}

// ---------------- Kernel 2: fused scores (MFMA) + top-k + softmax + probs + PV ----------------
// grid (512), block 1024 (16 waves). Block = 16 query rows of one head.
// id%8 -> XCD (round-robin heuristic); head = (id%8)>>1 so each XCD serves ONE head
// (1.25 MB working set, L2-resident).
// LDS: S[16][2048] f32 = 128 KB. Per-row overlay after topk: bytes [0,4096) = P bf16,
// bytes [4096,8192) = PV partials [16 rows][64 d] f32 (swizzled).
__global__ __launch_bounds__(1024, 4) void fused_attn_kernel(const ushort* __restrict__ wsu,
                                                             float* __restrict__ out)
{
    const int id = blockIdx.x;
    const int c8 = id & 7;
    const int h  = c8 >> 1;
    const int n0 = 16 * ((id >> 3) + 64 * (c8 & 1));
    float* sp = out + (size_t)NPTS*DM;
    __shared__ float S[16][NPTS];   // 131072 B

    const int w  = threadIdx.x >> 6, l = threadIdx.x & 63;
    const int cl = l & 15, cg = l >> 4;

    // ========== phase A: all 16 rows x cols [128w, 128w+128) ==========
    // Swapped operands: A = K (16 cols/tile), B = Q (16 rows, ALL used).
    // C[lane,reg]: q-row = cl, K-col = col0 + 16t + 4*cg + reg.
    {
        const size_t qbase = ((size_t)(h*NPTS + n0 + cl))*DH + 8*cg;
        bf16x8 qbh0 = *(const bf16x8*)(wsu + QH_OFF + qbase);
        bf16x8 qbl0 = *(const bf16x8*)(wsu + QL_OFF + qbase);
        bf16x8 qbh1 = *(const bf16x8*)(wsu + QH_OFF + qbase + 32);
        bf16x8 qbl1 = *(const bf16x8*)(wsu + QL_OFF + qbase + 32);

        const int col0 = 128*w;
        const ushort* khp = wsu + KH_OFF;
        const ushort* klp = wsu + KL_OFF;
        const size_t kb0 = ((size_t)(h*NPTS + col0 + cl))*DH + 8*cg;

        // register double-buffer over 8 t-tiles
        bf16x8 ah0 = *(const bf16x8*)(khp + kb0);
        bf16x8 al0 = *(const bf16x8*)(klp + kb0);
        bf16x8 ah1 = *(const bf16x8*)(khp + kb0 + 32);
        bf16x8 al1 = *(const bf16x8*)(klp + kb0 + 32);

        f32x4 acc[8];
        #pragma unroll
        for (int t = 0; t < 8; t++) {
            bf16x8 nh0, nl0, nh1, nl1;
            if (t < 7) {
                const size_t kn = kb0 + (size_t)(t+1)*(16*DH);
                nh0 = *(const bf16x8*)(khp + kn);
                nl0 = *(const bf16x8*)(klp + kn);
                nh1 = *(const bf16x8*)(khp + kn + 32);
                nl1 = *(const bf16x8*)(klp + kn + 32);
            }
            f32x4 a = {0.f, 0.f, 0.f, 0.f};
            a = __builtin_amdgcn_mfma_f32_16x16x32_bf16(ah0, qbh0, a, 0, 0, 0);
            a = __builtin_amdgcn_mfma_f32_16x16x32_bf16(ah0, qbl0, a, 0, 0, 0);
            a = __builtin_amdgcn_mfma_f32_16x16x32_bf16(al0, qbh0, a, 0, 0, 0);
            a = __builtin_amdgcn_mfma_f32_16x16x32_bf16(ah1, qbh1, a, 0, 0, 0);
            a = __builtin_amdgcn_mfma_f32_16x16x32_bf16(ah1, qbl1, a, 0, 0, 0);
            a = __builtin_amdgcn_mfma_f32_16x16x32_bf16(al1, qbh1, a, 0, 0, 0);
            acc[t] = a;
            ah0 = nh0; al0 = nl0; ah1 = nh1; al1 = nl1;
        }
        #pragma unroll
        for (int t = 0; t < 8; t++) {
            uint32_t byte = (512u*(uint32_t)w + 64u*(uint32_t)t + 16u*(uint32_t)cg)
                            ^ ((uint32_t)(cl & 7) << 4);
            *(f32x4*)((char*)&S[cl][0] + byte) = acc[t];
        }
    }

    // prefetch Vt A-frags for PV kstep 0 (no LDS dependency -> overlaps barrier+search)
    const ushort* Vt = wsu + VT_OFF + (size_t)h*DH*NPTS;
    const int m0 = 128*w;
    bf16x8 vpre[4];
    #pragma unroll
    for (int dt = 0; dt < 4; dt++)
        vpre[dt] = *(const bf16x8*)(Vt + ((size_t)(16*dt + cl))*NPTS + (m0 + 8*cg));

    __syncthreads();   // scores visible

    // ========== phase B: per-wave exact top-1024 + softmax on row w ==========
    const uint32_t sw = ((uint32_t)(w & 7)) << 4;
    uint32_t u[32];
    #pragma unroll
    for (int j = 0; j < 8; j++) {
        f32x4 v = *(const f32x4*)((const char*)&S[w][0] + ((16u*(uint32_t)(l + 64*j)) ^ sw));
        u[4*j+0] = f2u(v[0]); u[4*j+1] = f2u(v[1]); u[4*j+2] = f2u(v[2]); u[4*j+3] = f2u(v[3]);
    }

    // row max
    uint32_t mu = 0u;
    #pragma unroll
    for (int j = 0; j < 32; j++) mu = (u[j] > mu) ? u[j] : mu;
    #pragma unroll
    for (int off = 32; off; off >>= 1) {
        uint32_t o = (uint32_t)__shfl_xor((int)mu, off);
        mu = (o > mu) ? o : mu;
    }
    const float mx = u2f(mu);

    // 2-bit radix search for exact 1024-th largest key (16 dependent steps, early exit)
    uint32_t cur = 0u;
    for (int bit = 30; bit >= 0; bit -= 2) {
        const uint32_t cA = cur | (3u << bit);
        const uint32_t cB = cur | (2u << bit);
        const uint32_t cC = cur | (1u << bit);
        int nA = 0, nB = 0, nC = 0;
        #pragma unroll
        for (int j = 0; j < 32; j++) {
            nA += (int)__popcll(__ballot(u[j] >= cA));
            nB += (int)__popcll(__ballot(u[j] >= cB));
            nC += (int)__popcll(__ballot(u[j] >= cC));
        }
        if (nA >= KK)      { cur = cA; if (nA == KK) break; }
        else if (nB >= KK) { cur = cB; if (nB == KK) break; }
        else if (nC >= KK) { cur = cC; if (nC == KK) break; }
    }

    // softmax over selected; exp overwrites u[]
    float zsum = 0.f;
    #pragma unroll
    for (int j = 0; j < 32; j++) {
        bool sel = (u[j] >= cur);
        float ev = sel ? __expf(u2f(u[j]) - mx) : 0.f;
        u[j] = __float_as_uint(ev);
        zsum += ev;
    }
    #pragma unroll
    for (int off = 32; off; off >>= 1) zsum += __shfl_xor(zsum, off);
    const float rz = 1.f / zsum;

    // probs -> global (dense row) + bf16 P overlaid into own S row's first 4KB (swizzled)
    float* grow = sp + ((size_t)(h*NPTS + n0 + w))*NPTS;
    #pragma unroll
    for (int j = 0; j < 8; j++) {
        float4 p;
        p.x = __uint_as_float(u[4*j+0]) * rz;
        p.y = __uint_as_float(u[4*j+1]) * rz;
        p.z = __uint_as_float(u[4*j+2]) * rz;
        p.w = __uint_as_float(u[4*j+3]) * rz;
        ((float4*)grow)[l + 64*j] = p;
        uint32_t pk0 = ((uint32_t)bf16rn(p.y) << 16) | (uint32_t)bf16rn(p.x);
        uint32_t pk1 = ((uint32_t)bf16rn(p.w) << 16) | (uint32_t)bf16rn(p.z);
        *(uint2*)((char*)&S[w][0] + ((8u*(uint32_t)(l + 64*j)) ^ sw)) = make_uint2(pk0, pk1);
    }
    __syncthreads();   // all P rows ready

    // ========== phase C: PV via MFMA. wave w covers m in [128w, 128w+128) ==========
    // A = Vt (d-rows), B = P (16 q-rows, ALL cols used). C: q-row = cl, d = 16dt+4cg+reg.
    const char* pbase = (const char*)&S[cl][0];
    const uint32_t psw = ((uint32_t)(cl & 7)) << 4;
    f32x4 pacc[4];
    #pragma unroll
    for (int dt = 0; dt < 4; dt++) pacc[dt] = (f32x4){0.f, 0.f, 0.f, 0.f};

    {   // s = 0 uses prefetched A-frags
        bf16x8 bfrag = *(const bf16x8*)(pbase + ((2u*(uint32_t)(m0 + 8*cg)) ^ psw));
        #pragma unroll
        for (int dt = 0; dt < 4; dt++)
            pacc[dt] = __builtin_amdgcn_mfma_f32_16x16x32_bf16(vpre[dt], bfrag, pacc[dt], 0, 0, 0);
    }
    #pragma unroll
    for (int s = 1; s < 4; s++) {
        const int mk = m0 + 32*s + 8*cg;
        bf16x8 bfrag = *(const bf16x8*)(pbase + ((2u*(uint32_t)mk) ^ psw));
        #pragma unroll
        for (int dt = 0; dt < 4; dt++) {
            bf16x8 afrag = *(const bf16x8*)(Vt + ((size_t)(16*dt + cl))*NPTS + mk);
            pacc[dt] = __builtin_amdgcn_mfma_f32_16x16x32_bf16(afrag, bfrag, pacc[dt], 0, 0, 0);
        }
    }

    // partials into own row w's bytes [4096,8192): [qrow=cl][d], 16B-XOR swizzle by cl
    {
        char* part = (char*)S + (size_t)w*(NPTS*4) + 4096;
        #pragma unroll
        for (int dt = 0; dt < 4; dt++) {
            uint32_t byte = (uint32_t)cl*256u + ((64u*(uint32_t)dt + 16u*(uint32_t)cg)
                            ^ ((uint32_t)(cl & 7) << 4));
            *(f32x4*)(part + byte) = pacc[dt];
        }
    }
    __syncthreads();

    {   // final reduce: thread (r = tid>>6, d = tid&63) sums 16 wave-partials
        const int r = threadIdx.x >> 6, d = threadIdx.x & 63;
        const uint32_t byte = (uint32_t)r*256u + (((4u*(uint32_t)(d & ~3)) ^ ((uint32_t)(r & 7) << 4))
                              + 4u*(uint32_t)(d & 3));
        float ssum = 0.f;
        #pragma unroll
        for (int wv = 0; wv < 16; wv++)
            ssum += *(const float*)((const char*)S + (size_t)wv*(NPTS*4) + 4096 + byte);
        out[(size_t)(n0 + r)*DM + h*DH + d] = ssum;
    }
}

extern "C" void kernel_launch(void* const* d_in, const int* in_sizes, int n_in,
                              void* d_out, int out_size, void* d_ws, size_t ws_size,
                              hipStream_t stream)
{
    const float* xq  = (const float*)d_in[0];
    const float* xk  = (const float*)d_in[1];
    const float* xv  = (const float*)d_in[2];
    const float* emb = (const float*)d_in[3];
    const float* Wq  = (const float*)d_in[4];
    const float* bq  = (const float*)d_in[5];
    const float* Wk  = (const float*)d_in[6];
    const float* bk  = (const float*)d_in[7];
    const float* Wv  = (const float*)d_in[8];
    const float* bv  = (const float*)d_in[9];
    float* out  = (float*)d_out;
    ushort* wsu = (ushort*)d_ws;   // needs 5 MiB

    proj_rope_kernel<<<dim3(NPTS/8, 3), 256, 0, stream>>>(xq, xk, xv, emb, Wq, bq, Wk, bk, Wv, bv, wsu);
    fused_attn_kernel<<<dim3(NPTS/16 * NH), 1024, 0, stream>>>(wsu, out);
}

// Round 8
// 98.615 us; speedup vs baseline: 1.4518x; 1.1615x over previous
//
#include <hip/hip_runtime.h>
#include <hip/hip_bf16.h>
#include <stdint.h>

#define NPTS 2048
#define DM 256
#define NH 4
#define DH 64
#define KK 1024

// ws layout (ushort units):
//  Qh bf16 [4][2048][64] @ 0
//  Ql bf16               @ 1*524288
//  Kh bf16               @ 2*524288
//  Kl bf16               @ 3*524288
//  Vt bf16 [4][64][2048] @ 4*524288   (transposed: channel-major)
#define QH_OFF 0
#define QL_OFF (NH*NPTS*DH)
#define KH_OFF (2*NH*NPTS*DH)
#define KL_OFF (3*NH*NPTS*DH)
#define VT_OFF (4*NH*NPTS*DH)

typedef __attribute__((ext_vector_type(8)))  short bf16x8;
typedef __attribute__((ext_vector_type(4)))  float f32x4;

__device__ inline ushort bf16rn(float f) {
    uint32_t u = __float_as_uint(f);
    uint32_t r = (u + 0x7FFFu + ((u >> 16) & 1u)) >> 16;
    return (ushort)r;
}
__device__ inline float bf16tof(ushort h) {
    return __uint_as_float(((uint32_t)h) << 16);
}
__device__ inline uint32_t f2u(float f) {
    uint32_t x = __float_as_uint(f);
    return (x & 0x80000000u) ? ~x : (x | 0x80000000u);
}
__device__ inline float u2f(uint32_t u) {
    uint32_t x = (u & 0x80000000u) ? (u ^ 0x80000000u) : ~u;
    return __uint_as_float(x);
}

// ---------------- Kernel 1: projections + rotary + bf16 hi/lo split + V^T ----------------
__global__ __launch_bounds__(256) void proj_rope_kernel(
    const float* __restrict__ xq, const float* __restrict__ xk, const float* __restrict__ xv,
    const float* __restrict__ emb,
    const float* __restrict__ Wq, const float* __restrict__ bq,
    const float* __restrict__ Wk, const float* __restrict__ bk,
    const float* __restrict__ Wv, const float* __restrict__ bv,
    ushort* __restrict__ wsu)
{
    const int z = blockIdx.y;
    const int n0 = blockIdx.x * 8;
    const float* X = (z==0) ? xq : (z==1) ? xk : xv;
    const float* W = (z==0) ? Wq : (z==1) ? Wk : Wv;
    const float* B = (z==0) ? bq : (z==1) ? bk : bv;

    __shared__ float s_in[8][DM];
    {
        const float4* X4 = (const float4*)(X + (size_t)n0 * DM);
        float4* s4 = (float4*)&s_in[0][0];
        #pragma unroll
        for (int i = 0; i < 2; i++) {
            int f = threadIdx.x + 256*i;
            s4[f] = X4[f];
        }
    }
    __syncthreads();

    const int c = threadIdx.x;
    const int h = c >> 6, d = c & 63;
    const float bias = B[c];
    float acc[8];
    #pragma unroll
    for (int r = 0; r < 8; r++) acc[r] = bias;

    const float4* W4 = (const float4*)(W + (size_t)c * DM);
    #pragma unroll 4
    for (int k4 = 0; k4 < DM/4; k4++) {
        float4 w = W4[k4];
        #pragma unroll
        for (int r = 0; r < 8; r++) {
            float4 sv = *(const float4*)&s_in[r][k4*4];
            acc[r] = fmaf(sv.x, w.x, acc[r]);
            acc[r] = fmaf(sv.y, w.y, acc[r]);
            acc[r] = fmaf(sv.z, w.z, acc[r]);
            acc[r] = fmaf(sv.w, w.w, acc[r]);
        }
    }

    if (z < 2) {
        const int p = d >> 1;
        #pragma unroll
        for (int r = 0; r < 8; r++) {
            float th = emb[(size_t)(n0 + r)*(DM/2) + h*32 + p];
            float cs = cosf(th), sn = sinf(th);
            float partner = __shfl_xor(acc[r], 1);
            acc[r] = (d & 1) ? (acc[r]*cs + partner*sn) : (acc[r]*cs - partner*sn);
            if (z == 0) acc[r] *= 0.125f;   // 1/sqrt(64) folded into Q
        }
        ushort* hi = wsu + ((z==0) ? QH_OFF : KH_OFF);
        ushort* lo = wsu + ((z==0) ? QL_OFF : KL_OFF);
        #pragma unroll
        for (int r = 0; r < 8; r++) {
            size_t idx = ((size_t)(h*NPTS + n0 + r))*DH + d;
            ushort hb = bf16rn(acc[r]);
            float res = acc[r] - bf16tof(hb);
            hi[idx] = hb;
            lo[idx] = bf16rn(res);
        }
    } else {
        __syncthreads();
        #pragma unroll
        for (int r = 0; r < 8; r++) s_in[r][c] = acc[r];
        __syncthreads();
        ushort tmp[8];
        #pragma unroll
        for (int r = 0; r < 8; r++) tmp[r] = bf16rn(s_in[r][c]);
        *(bf16x8*)(wsu + VT_OFF + (size_t)c*NPTS + n0) = *(bf16x8*)tmp;
    }
}

// ---------------- Kernel 2: fused scores + top-k + softmax + probs + PV ----------------
// grid (512), block 1024 (16 waves) = 16 query rows of one head.
// LDS: ONE 64 KB buffer, time-multiplexed:
//   phase A: S-staging [16 rows][1024 cols] f32 (two column passes)
//   phase B: P bf16 [16][2048] (row w written only by wave w)
//   phase C: PV partials [16 waves][16 rows][64 d] f32
// 64 KB -> 2 blocks/CU -> 8 waves/SIMD. launch_bounds forces <=64 VGPR.
__global__ __launch_bounds__(1024, 8) void fused_attn_kernel(const ushort* __restrict__ wsu,
                                                             float* __restrict__ out)
{
    const int id = blockIdx.x;
    const int c8 = id & 7;                      // XCD (round-robin heuristic)
    const int h  = c8 >> 1;                     // one head per XCD pair
    const int n0 = 16 * ((id >> 3) + 64 * (c8 & 1));
    float* sp = out + (size_t)NPTS*DM;
    __shared__ float LB[16384];                 // 65536 B
    char* lds = (char*)LB;

    const int w  = threadIdx.x >> 6, l = threadIdx.x & 63;
    const int cl = l & 15, cg = l >> 4;
    const uint32_t rsw = ((uint32_t)(cl & 7)) << 4;   // swizzle keyed by per-lane row cl
    const uint32_t wsw = ((uint32_t)(w  & 7)) << 4;   // swizzle keyed by own row w

    // Q fragments (B operand): q-row = cl, k = 8*cg + i (+32s). Same k-map as A side.
    const size_t qbase = ((size_t)(h*NPTS + n0 + cl))*DH + 8*cg;
    const bf16x8 qh0 = *(const bf16x8*)(wsu + QH_OFF + qbase);
    const bf16x8 ql0 = *(const bf16x8*)(wsu + QL_OFF + qbase);
    const bf16x8 qh1 = *(const bf16x8*)(wsu + QH_OFF + qbase + 32);
    const bf16x8 ql1 = *(const bf16x8*)(wsu + QL_OFF + qbase + 32);

    uint32_t u[32];   // this wave's full score row (as monotone uint keys)

    // ========== phase A: two column passes through the 64 KB staging buffer ==========
    #pragma unroll
    for (int p = 0; p < 2; p++) {
        const int col0 = 1024*p + 64*w;         // this wave's 64-col strip in pass p
        #pragma unroll
        for (int t = 0; t < 4; t++) {
            const size_t kb = ((size_t)(h*NPTS + col0 + 16*t + cl))*DH + 8*cg;
            bf16x8 ah0 = *(const bf16x8*)(wsu + KH_OFF + kb);
            bf16x8 al0 = *(const bf16x8*)(wsu + KL_OFF + kb);
            bf16x8 ah1 = *(const bf16x8*)(wsu + KH_OFF + kb + 32);
            bf16x8 al1 = *(const bf16x8*)(wsu + KL_OFF + kb + 32);
            f32x4 a = {0.f, 0.f, 0.f, 0.f};
            a = __builtin_amdgcn_mfma_f32_16x16x32_bf16(ah0, qh0, a, 0, 0, 0);
            a = __builtin_amdgcn_mfma_f32_16x16x32_bf16(ah0, ql0, a, 0, 0, 0);
            a = __builtin_amdgcn_mfma_f32_16x16x32_bf16(al0, qh0, a, 0, 0, 0);
            a = __builtin_amdgcn_mfma_f32_16x16x32_bf16(ah1, qh1, a, 0, 0, 0);
            a = __builtin_amdgcn_mfma_f32_16x16x32_bf16(ah1, ql1, a, 0, 0, 0);
            a = __builtin_amdgcn_mfma_f32_16x16x32_bf16(al1, qh1, a, 0, 0, 0);
            // C: q-row = cl, k-col-in-pass = 64w + 16t + 4cg + reg
            uint32_t byte = (uint32_t)cl*4096u +
                ((256u*(uint32_t)w + 64u*(uint32_t)t + 16u*(uint32_t)cg) ^ rsw);
            *(f32x4*)(lds + byte) = a;          // store per-t: keeps acc live-range = 1
        }
        __syncthreads();                        // staging pass p complete
        #pragma unroll
        for (int j = 0; j < 4; j++) {           // wave w reads its own row's half
            f32x4 v = *(const f32x4*)(lds + (size_t)w*4096u +
                        ((16u*(uint32_t)(l + 64*j)) ^ wsw));
            u[16*p + 4*j + 0] = f2u(v[0]);
            u[16*p + 4*j + 1] = f2u(v[1]);
            u[16*p + 4*j + 2] = f2u(v[2]);
            u[16*p + 4*j + 3] = f2u(v[3]);
        }
        if (p == 0) __syncthreads();            // reads done before pass-1 overwrite
        // (after pass 1: row w touched only by wave w -> no barrier needed)
    }

    // ========== phase B: in-register exact top-1024 + softmax ==========
    uint32_t mu = 0u;
    #pragma unroll
    for (int j = 0; j < 32; j++) mu = (u[j] > mu) ? u[j] : mu;
    #pragma unroll
    for (int off = 32; off; off >>= 1) {
        uint32_t o = (uint32_t)__shfl_xor((int)mu, off);
        mu = (o > mu) ? o : mu;
    }
    const float mx = u2f(mu);

    // 1-bit binary search (ballot+popcount), early exit on exact count
    uint32_t cur = 0u;
    for (int bit = 31; bit >= 0; bit--) {
        uint32_t cand = cur | (1u << bit);
        int c = 0;
        #pragma unroll
        for (int j = 0; j < 32; j++) c += (int)__popcll(__ballot(u[j] >= cand));
        if (c >= KK) { cur = cand; if (c == KK) break; }
    }

    // softmax numerators overwrite u[]
    float zsum = 0.f;
    #pragma unroll
    for (int j = 0; j < 32; j++) {
        bool sel = (u[j] >= cur);
        float ev = sel ? __expf(u2f(u[j]) - mx) : 0.f;
        u[j] = __float_as_uint(ev);
        zsum += ev;
    }
    #pragma unroll
    for (int off = 32; off; off >>= 1) zsum += __shfl_xor(zsum, off);
    const float rz = 1.f / zsum;

    // P bf16 into own row w of the (reused) 64 KB buffer: col c at byte 2c ^ wsw
    #pragma unroll
    for (int p2 = 0; p2 < 2; p2++)
        #pragma unroll
        for (int j = 0; j < 4; j++) {
            const int b = 16*p2 + 4*j;
            float p0 = __uint_as_float(u[b+0]) * rz;
            float p1 = __uint_as_float(u[b+1]) * rz;
            float p2v = __uint_as_float(u[b+2]) * rz;
            float p3 = __uint_as_float(u[b+3]) * rz;
            uint32_t pk0 = ((uint32_t)bf16rn(p1) << 16) | (uint32_t)bf16rn(p0);
            uint32_t pk1 = ((uint32_t)bf16rn(p3) << 16) | (uint32_t)bf16rn(p2v);
            *(uint2*)(lds + (size_t)w*4096u +
                ((2048u*(uint32_t)p2 + 8u*(uint32_t)(l + 64*j)) ^ wsw)) = make_uint2(pk0, pk1);
        }
    __syncthreads();                            // all P rows ready

    // prob global stores (nontemporal, streaming) — drain under PV compute
    {
        f32x4* grow = (f32x4*)(sp + ((size_t)(h*NPTS + n0 + w))*NPTS);
        #pragma unroll
        for (int p2 = 0; p2 < 2; p2++)
            #pragma unroll
            for (int j = 0; j < 4; j++) {
                const int b = 16*p2 + 4*j;
                f32x4 pv;
                pv[0] = __uint_as_float(u[b+0]) * rz;
                pv[1] = __uint_as_float(u[b+1]) * rz;
                pv[2] = __uint_as_float(u[b+2]) * rz;
                pv[3] = __uint_as_float(u[b+3]) * rz;
                __builtin_nontemporal_store(pv, grow + 256*p2 + l + 64*j);
            }
    }

    // ========== phase C: PV via MFMA; wave w covers m in [128w, 128w+128) ==========
    const ushort* Vt = wsu + VT_OFF + (size_t)h*DH*NPTS;
    const int m0 = 128*w;
    f32x4 pacc[4];
    #pragma unroll
    for (int dt = 0; dt < 4; dt++) pacc[dt] = (f32x4){0.f, 0.f, 0.f, 0.f};

    #pragma unroll
    for (int s = 0; s < 4; s++) {
        const int mk = m0 + 32*s + 8*cg;
        bf16x8 bfrag = *(const bf16x8*)(lds + (size_t)cl*4096u + ((2u*(uint32_t)mk) ^ rsw));
        #pragma unroll
        for (int dt = 0; dt < 4; dt++) {
            bf16x8 afrag = *(const bf16x8*)(Vt + ((size_t)(16*dt + cl))*NPTS + mk);
            pacc[dt] = __builtin_amdgcn_mfma_f32_16x16x32_bf16(afrag, bfrag, pacc[dt], 0, 0, 0);
        }
    }
    __syncthreads();                            // all PV P-reads done; reuse buffer for partials

    // partials: [wave w][q-row cl][d], C layout d = 16dt + 4cg + reg
    #pragma unroll
    for (int dt = 0; dt < 4; dt++) {
        uint32_t byte = (uint32_t)w*4096u + (uint32_t)cl*256u +
            ((64u*(uint32_t)dt + 16u*(uint32_t)cg) ^ rsw);
        *(f32x4*)(lds + byte) = pacc[dt];
    }
    __syncthreads();

    {   // final reduce: wave r sums row r across the 16 wave-partials
        const int r = w, d = l;
        const uint32_t byte = (uint32_t)r*256u +
            ((4u*(uint32_t)(d & ~3)) ^ ((uint32_t)(r & 7) << 4)) + 4u*(uint32_t)(d & 3);
        float ssum = 0.f;
        #pragma unroll
        for (int wv = 0; wv < 16; wv++)
            ssum += *(const float*)(lds + (size_t)wv*4096u + byte);
        out[(size_t)(n0 + r)*DM + h*DH + d] = ssum;
    }
}

extern "C" void kernel_launch(void* const* d_in, const int* in_sizes, int n_in,
                              void* d_out, int out_size, void* d_ws, size_t ws_size,
                              hipStream_t stream)
{
    const float* xq  = (const float*)d_in[0];
    const float* xk  = (const float*)d_in[1];
    const float* xv  = (const float*)d_in[2];
    const float* emb = (const float*)d_in[3];
    const float* Wq  = (const float*)d_in[4];
    const float* bq  = (const float*)d_in[5];
    const float* Wk  = (const float*)d_in[6];
    const float* bk  = (const float*)d_in[7];
    const float* Wv  = (const float*)d_in[8];
    const float* bv  = (const float*)d_in[9];
    float* out  = (float*)d_out;
    ushort* wsu = (ushort*)d_ws;   // needs 5 MiB

    proj_rope_kernel<<<dim3(NPTS/8, 3), 256, 0, stream>>>(xq, xk, xv, emb, Wq, bq, Wk, bk, Wv, bv, wsu);
    fused_attn_kernel<<<dim3(NPTS/16 * NH), 1024, 0, stream>>>(wsu, out);
}